// Round 1
// baseline (521.863 us; speedup 1.0000x reference)
//
#include <hip/hip_runtime.h>

// SSIM3D: input/target (2,1,192,192,192) fp32, 7^3 Gaussian (separable), valid conv -> 186^3, mean.
// Strategy: fused single kernel. Per block: 8^3 output tile, stage 14^3 x/y halo tile in LDS,
// separable conv (z,y,x passes) of 5 fields {x, y, x^2, y^2, xy} with register sliding windows,
// SSIM map + block reduce + double atomicAdd into d_ws; finalize kernel divides.

#define R 7
#define T 8
#define IN_T 14          // T + 6 halo
#define DIMS 192
#define OD 186
#define NTILE 24         // ceil(186/8)

// LDS layout (floats), 14700 floats = 57.4 KiB:
//   stage:  sx at 0      : [14][14][15]  (2940)
//           sy at 2940   : [14][14][15]  (2940)
//   zbuf at 5880 : [5][14*14][9]  f*1764 + (i*14+j)*9 + k   (8820)  -- z-convolved
//   ybuf at 0    : [5][14][8][9]  f*1008 + (i*8+j)*9 + k    (5040)  -- overlays stage (dead)
//   xbuf at 5880 : [5][8][8][9]   f*576  + (i*8+j)*9 + k    (2880)  -- overlays zbuf (dead)
#define SX_OFF 0
#define SY_OFF 2940
#define ZB_OFF 5880
#define YB_OFF 0
#define XB_OFF 5880
#define LDS_FLOATS 14700

__global__ __launch_bounds__(256)
void ssim3d_kernel(const float* __restrict__ x, const float* __restrict__ y,
                   double* __restrict__ acc) {
    __shared__ float lds[LDS_FLOATS];
    __shared__ float wsum[4];
    const int tid = threadIdx.x;

    // 1D Gaussian softmax weights (separable: softmax(gi+gj+gk) = w[i]w[j]w[k])
    float w[R];
    {
        float s = 0.f;
        #pragma unroll
        for (int t = 0; t < R; ++t) {
            float d = (float)t - 3.0f;
            w[t] = expf(-d * d / 4.5f);   // sigma=1.5 -> 2*sigma^2 = 4.5
            s += w[t];
        }
        #pragma unroll
        for (int t = 0; t < R; ++t) w[t] /= s;
    }

    const int oz = blockIdx.x * T;               // W (contiguous)
    const int oy = blockIdx.y * T;               // H
    const int tx = blockIdx.z % NTILE;
    const int n  = blockIdx.z / NTILE;
    const int ox = tx * T;                       // D
    const long long VOL = (long long)DIMS * DIMS * DIMS;
    const float* xb = x + (long long)n * VOL;
    const float* yb = y + (long long)n * VOL;

    // ---- stage x,y halo tile (14^3), clamp OOB (values only feed invalid outputs) ----
    for (int idx = tid; idx < IN_T * IN_T * IN_T; idx += 256) {
        int i = idx / (IN_T * IN_T);
        int r = idx % (IN_T * IN_T);
        int j = r / IN_T, k = r % IN_T;
        int gx = min(ox + i, DIMS - 1);
        int gy = min(oy + j, DIMS - 1);
        int gz = min(oz + k, DIMS - 1);
        long long g = ((long long)gx * DIMS + gy) * DIMS + gz;
        lds[SX_OFF + (i * IN_T + j) * 15 + k] = xb[g];
        lds[SY_OFF + (i * IN_T + j) * 15 + k] = yb[g];
    }
    __syncthreads();

    // ---- Z pass: one thread per (i,j) pencil; sliding window in registers ----
    if (tid < IN_T * IN_T) {
        int i = tid / IN_T, j = tid % IN_T;
        const float* px = &lds[SX_OFF + (i * IN_T + j) * 15];
        const float* py = &lds[SY_OFF + (i * IN_T + j) * 15];
        float xv[IN_T], yv[IN_T];
        #pragma unroll
        for (int k = 0; k < IN_T; ++k) { xv[k] = px[k]; yv[k] = py[k]; }
        float* zb = &lds[ZB_OFF + (i * IN_T + j) * 9];
        #pragma unroll
        for (int k = 0; k < T; ++k) {
            float a0 = 0, a1 = 0, a2 = 0, a3 = 0, a4 = 0;
            #pragma unroll
            for (int t = 0; t < R; ++t) {
                float xx = xv[k + t], yy = yv[k + t], wt = w[t];
                a0 += wt * xx;
                a1 += wt * yy;
                a2 += wt * (xx * xx);
                a3 += wt * (yy * yy);
                a4 += wt * (xx * yy);
            }
            zb[0 * 1764 + k] = a0;
            zb[1 * 1764 + k] = a1;
            zb[2 * 1764 + k] = a2;
            zb[3 * 1764 + k] = a3;
            zb[4 * 1764 + k] = a4;
        }
    }
    __syncthreads();

    // ---- Y pass: one thread per (f,i,k); slide over j ----
    for (int idx = tid; idx < 5 * IN_T * T; idx += 256) {   // 560 tasks
        int f = idx / (IN_T * T);
        int r = idx % (IN_T * T);
        int i = r / T, k = r % T;
        const float* src = &lds[ZB_OFF + f * 1764 + (i * IN_T) * 9 + k];
        float v[IN_T];
        #pragma unroll
        for (int j = 0; j < IN_T; ++j) v[j] = src[j * 9];
        float* dst = &lds[YB_OFF + f * 1008 + (i * T) * 9 + k];
        #pragma unroll
        for (int j = 0; j < T; ++j) {
            float a = 0;
            #pragma unroll
            for (int t = 0; t < R; ++t) a += w[t] * v[j + t];
            dst[j * 9] = a;
        }
    }
    __syncthreads();

    // ---- X pass: one thread per (f,j,k); slide over i ----
    for (int idx = tid; idx < 5 * T * T; idx += 256) {      // 320 tasks
        int f = idx / (T * T);
        int r = idx % (T * T);
        int j = r / T, k = r % T;
        const float* src = &lds[YB_OFF + f * 1008 + j * 9 + k];
        float v[IN_T];
        #pragma unroll
        for (int i = 0; i < IN_T; ++i) v[i] = src[i * 72];
        float* dst = &lds[XB_OFF + f * 576 + j * 9 + k];
        #pragma unroll
        for (int i = 0; i < T; ++i) {
            float a = 0;
            #pragma unroll
            for (int t = 0; t < R; ++t) a += w[t] * v[i + t];
            dst[i * 72] = a;
        }
    }
    __syncthreads();

    // ---- SSIM map + reduction ----
    const float c1 = 1e-4f;   // (0.01*1.0)^2
    const float c2 = 9e-4f;   // (0.03*1.0)^2
    float lsum = 0.f;
    for (int idx = tid; idx < T * T * T; idx += 256) {
        int i = idx / 64, r = idx % 64, j = r / 8, k = r % 8;
        if (ox + i < OD && oy + j < OD && oz + k < OD) {
            int b = (i * T + j) * 9 + k;
            float mu1 = lds[XB_OFF + 0 * 576 + b];
            float mu2 = lds[XB_OFF + 1 * 576 + b];
            float ex2 = lds[XB_OFF + 2 * 576 + b];
            float ey2 = lds[XB_OFF + 3 * 576 + b];
            float exy = lds[XB_OFF + 4 * 576 + b];
            float mu11 = mu1 * mu1, mu22 = mu2 * mu2, mu12 = mu1 * mu2;
            float s1 = ex2 - mu11, s2 = ey2 - mu22, s12 = exy - mu12;
            float num = (2.f * mu12 + c1) * (2.f * s12 + c2);
            float den = (mu11 + mu22 + c1) * (s1 + s2 + c2);
            lsum += num / den;
        }
    }
    // wave64 butterfly + cross-wave via LDS
    #pragma unroll
    for (int off = 32; off > 0; off >>= 1) lsum += __shfl_down(lsum, off, 64);
    if ((tid & 63) == 0) wsum[tid >> 6] = lsum;
    __syncthreads();
    if (tid == 0) {
        float bs = wsum[0] + wsum[1] + wsum[2] + wsum[3];
        atomicAdd(acc, (double)bs);
    }
}

__global__ void ssim3d_finalize(const double* __restrict__ acc, float* __restrict__ out) {
    out[0] = (float)(acc[0] / 12869712.0);   // 2 * 186^3
}

extern "C" void kernel_launch(void* const* d_in, const int* in_sizes, int n_in,
                              void* d_out, int out_size, void* d_ws, size_t ws_size,
                              hipStream_t stream) {
    (void)in_sizes; (void)n_in; (void)out_size; (void)ws_size;
    const float* x = (const float*)d_in[0];
    const float* y = (const float*)d_in[1];
    float* out = (float*)d_out;
    double* acc = (double*)d_ws;
    hipMemsetAsync(d_ws, 0, sizeof(double), stream);
    dim3 grid(NTILE, NTILE, NTILE * 2);
    ssim3d_kernel<<<grid, 256, 0, stream>>>(x, y, acc);
    ssim3d_finalize<<<1, 1, 0, stream>>>(acc, out);
}

// Round 2
// 400.249 us; speedup vs baseline: 1.3038x; 1.3038x over previous
//
#include <hip/hip_runtime.h>

// SSIM3D fused, plane-march version.
// Grid: z-tiles(3) x y-tiles(24) x (x-chunks(3) * batch(2)). Block = 256 threads.
// Block owns output slab y0..y0+7, z0..z0+61 and marches 68 input planes along x.
// Per plane: stage raw 14x68 (x,y) -> z-conv (5 fields, reg sliding window)
// -> y-conv -> accumulate into 7-deep register ring (incremental x-conv).
// Ring slot 0 completes one 8x62 output plane per step: SSIM + local sum.
// Block reduce -> double atomicAdd -> finalize kernel divides by 2*186^3.

#define DIMS 192
#define OD   186
#define CH   62      // output tile along z and x-chunk size (186 = 3*62)
#define NP   68      // input planes per x-chunk = CH + 6
#define YT   8       // output rows per block
#define YIN  14      // input rows = YT + 6

// LDS layout (floats)
#define ST_OFF 0      // stage[2][14][73]  (row pad 73 -> 2-way-free z-conv reads)
#define ST_F   1022   // 14*73
#define ST_J   73
#define ZP_OFF 2048   // zplane[5][14][64], k swizzled by +17*j (write conflicts ~2-way)
#define ZP_F   896    // 14*64
#define YP_OFF 6528   // yplane[5][8][64]
#define YP_F   512    // 8*64
#define LDS_N  9088

__global__ __launch_bounds__(256, 4)
void ssim3d_kernel(const float* __restrict__ X, const float* __restrict__ Y,
                   double* __restrict__ acc_out) {
    __shared__ float lds[LDS_N];
    __shared__ float wsum[4];
    const int tid = threadIdx.x;

    // 1D Gaussian softmax weights (separable); push to SGPR (wave-uniform).
    float w[7];
    {
        float s = 0.f;
        #pragma unroll
        for (int t = 0; t < 7; ++t) {
            float d = (float)t - 3.0f;
            w[t] = expf(-d * d / 4.5f);   // sigma=1.5 -> 2*sigma^2=4.5
            s += w[t];
        }
        #pragma unroll
        for (int t = 0; t < 7; ++t)
            w[t] = __uint_as_float(__builtin_amdgcn_readfirstlane(__float_as_uint(w[t] / s)));
    }

    const int z0 = blockIdx.x * CH;          // output z start == input z start
    const int y0 = blockIdx.y * YT;
    const int cx = blockIdx.z % 3;
    const int n  = blockIdx.z / 3;
    const int x0 = cx * CH;                  // input x start

    const float* Xb = X + (size_t)n * (DIMS * DIMS * DIMS);
    const float* Yb = Y + (size_t)n * (DIMS * DIMS * DIMS);

    // x-conv ring accumulators: acc[q][2f+pt], slot q holds output plane o = xi-6+q
    float acc[7][10];
    #pragma unroll
    for (int q = 0; q < 7; ++q)
        #pragma unroll
        for (int m = 0; m < 10; ++m) acc[q][m] = 0.f;

    // accumulate-phase point ownership: (aj, ak) and (aj+4, ak)
    const int aj = tid >> 6;                 // 0..3 (wave-uniform)
    const int ak = tid & 63;
    const bool v1 = (ak < CH) && (y0 + aj < OD);
    const bool v2 = (ak < CH) && (y0 + aj + 4 < OD);

    // z-conv ownership: row zj, k-segment zs*4..zs*4+3
    const int zj = tid >> 4;                 // 0..15 (valid < 14)
    const int zs = tid & 15;

    float lsum = 0.f;
    const float c1 = 1e-4f, c2 = 9e-4f;

    for (int xi = 0; xi < NP; ++xi) {
        // ---- stage raw plane (both fields), rows y0..y0+13 clamped, z0..z0+67 ----
        const int gx = x0 + xi;              // always < 192
        const size_t pbase = (size_t)gx * (DIMS * DIMS) + z0;
        #pragma unroll
        for (int it = 0; it < 8; ++it) {
            int idx = tid + it * 256;
            if (idx < 2 * YIN * 68) {
                int fld = idx / (YIN * 68);
                int r   = idx - fld * (YIN * 68);
                int j   = r / 68;
                int z   = r - j * 68;
                int gy  = min(y0 + j, DIMS - 1);
                const float* src = fld ? Yb : Xb;
                lds[ST_OFF + fld * ST_F + j * ST_J + z] = src[pbase + (size_t)gy * DIMS + z];
            }
        }
        __syncthreads();

        // ---- z-conv: 5 fields, sliding window over 4 outputs per thread ----
        if (zj < YIN) {
            float xv[10], yv[10];
            const float* px = &lds[ST_OFF + zj * ST_J + zs * 4];
            const float* py = px + ST_F;
            #pragma unroll
            for (int t = 0; t < 10; ++t) { xv[t] = px[t]; yv[t] = py[t]; }
            const int swb = ZP_OFF + zj * 64;
            #pragma unroll
            for (int o = 0; o < 4; ++o) {
                int k = zs * 4 + o;
                float a0 = 0.f, a1 = 0.f, a2 = 0.f, a3 = 0.f, a4 = 0.f;
                #pragma unroll
                for (int t = 0; t < 7; ++t) {
                    float xx = xv[o + t], yy = yv[o + t], wt = w[t];
                    a0 += wt * xx;
                    a1 += wt * yy;
                    a2 += wt * (xx * xx);
                    a3 += wt * (yy * yy);
                    a4 += wt * (xx * yy);
                }
                if (k < CH) {
                    int b = swb + ((k + 17 * zj) & 63);
                    lds[b]            = a0;
                    lds[b + ZP_F]     = a1;
                    lds[b + 2 * ZP_F] = a2;
                    lds[b + 3 * ZP_F] = a3;
                    lds[b + 4 * ZP_F] = a4;
                }
            }
        }
        __syncthreads();

        // ---- y-conv: task = (field f, column k); 310 tasks ----
        #pragma unroll
        for (int pass = 0; pass < 2; ++pass) {
            int idx = tid + pass * 256;
            if (idx < 5 * CH) {
                int f = idx / CH;
                int k = idx - f * CH;
                float v[YIN];
                const int fb = ZP_OFF + f * ZP_F;
                #pragma unroll
                for (int jj = 0; jj < YIN; ++jj)
                    v[jj] = lds[fb + jj * 64 + ((k + 17 * jj) & 63)];
                const int ob = YP_OFF + f * YP_F + k;
                #pragma unroll
                for (int j = 0; j < YT; ++j) {
                    float a = 0.f;
                    #pragma unroll
                    for (int t = 0; t < 7; ++t) a += w[t] * v[j + t];
                    lds[ob + j * 64] = a;
                }
            }
        }
        __syncthreads();

        // ---- accumulate into x-conv ring; slot q gets w[6-q] ----
        float vv[10];
        #pragma unroll
        for (int f = 0; f < 5; ++f) {
            vv[2 * f]     = lds[YP_OFF + f * YP_F + aj * 64 + ak];
            vv[2 * f + 1] = lds[YP_OFF + f * YP_F + (aj + 4) * 64 + ak];
        }
        #pragma unroll
        for (int q = 0; q < 7; ++q) {
            float wq = w[6 - q];
            #pragma unroll
            for (int m = 0; m < 10; ++m) acc[q][m] += wq * vv[m];
        }

        // ---- slot 0 complete: SSIM for output plane o = xi-6 ----
        if (xi >= 6) {
            #pragma unroll
            for (int pt = 0; pt < 2; ++pt) {
                bool valid = pt ? v2 : v1;
                if (valid) {
                    float mu1 = acc[0][0 + pt], mu2 = acc[0][2 + pt];
                    float ex2 = acc[0][4 + pt], ey2 = acc[0][6 + pt], exy = acc[0][8 + pt];
                    float mu11 = mu1 * mu1, mu22 = mu2 * mu2, mu12 = mu1 * mu2;
                    float s1 = ex2 - mu11, s2 = ey2 - mu22, s12 = exy - mu12;
                    float num = (2.f * mu12 + c1) * (2.f * s12 + c2);
                    float den = (mu11 + mu22 + c1) * ((s1 + s2) + c2);
                    lsum += num / den;
                }
            }
        }

        // ---- shift ring ----
        #pragma unroll
        for (int q = 0; q < 6; ++q)
            #pragma unroll
            for (int m = 0; m < 10; ++m) acc[q][m] = acc[q + 1][m];
        #pragma unroll
        for (int m = 0; m < 10; ++m) acc[6][m] = 0.f;
        // no barrier needed: next stage writes only ST region (disjoint from YP reads)
    }

    // ---- block reduction ----
    #pragma unroll
    for (int off = 32; off > 0; off >>= 1) lsum += __shfl_down(lsum, off, 64);
    if ((tid & 63) == 0) wsum[tid >> 6] = lsum;
    __syncthreads();
    if (tid == 0)
        atomicAdd(acc_out, (double)(wsum[0] + wsum[1] + wsum[2] + wsum[3]));
}

__global__ void ssim3d_finalize(const double* __restrict__ acc, float* __restrict__ out) {
    out[0] = (float)(acc[0] / 12869712.0);   // 2 * 186^3
}

extern "C" void kernel_launch(void* const* d_in, const int* in_sizes, int n_in,
                              void* d_out, int out_size, void* d_ws, size_t ws_size,
                              hipStream_t stream) {
    (void)in_sizes; (void)n_in; (void)out_size; (void)ws_size;
    const float* x = (const float*)d_in[0];
    const float* y = (const float*)d_in[1];
    float* out = (float*)d_out;
    double* acc = (double*)d_ws;
    hipMemsetAsync(d_ws, 0, sizeof(double), stream);
    dim3 grid(3, 24, 6);   // z-tiles, y-tiles, x-chunks*batch
    ssim3d_kernel<<<grid, 256, 0, stream>>>(x, y, acc);
    ssim3d_finalize<<<1, 1, 0, stream>>>(acc, out);
}